// Round 18
// baseline (398.195 us; speedup 1.0000x reference)
//
#include <hip/hip_runtime.h>

#define DIM 512
#define B_  64
#define L_  2048

typedef unsigned short u16;
typedef float f32x4 __attribute__((ext_vector_type(4)));
typedef short s16x8 __attribute__((ext_vector_type(8)));
typedef short s16x4 __attribute__((ext_vector_type(4)));

// counted barrier: LDS ordering only, vmem (stores/prefetch) stays in flight
#define LGKM_BAR()                                          \
  do {                                                      \
    asm volatile("s_waitcnt lgkmcnt(0)" ::: "memory");      \
    __builtin_amdgcn_s_barrier();                           \
    __builtin_amdgcn_sched_barrier(0);                      \
  } while (0)

__device__ __forceinline__ u16 f2bf(float f) {
  union { float f; unsigned u; } x{f};
  unsigned r = x.u + 0x7FFFu + ((x.u >> 16) & 1u);
  return (u16)(r >> 16);
}

__device__ __forceinline__ float tanh_fast(float x) {
  float e2 = __expf(2.0f * x);
  return 1.0f - 2.0f / (e2 + 1.0f);
}

// ---------- prep: q = query @ Wq^T + bq ; Wr -> bf16 transposed [t][o][32k] ----------
__global__ __launch_bounds__(256) void prep_kernel(
    const float* __restrict__ query, const float* __restrict__ Wq,
    const float* __restrict__ bq, const float* __restrict__ Wr,
    float* __restrict__ q_out, u16* __restrict__ Wrbt) {
  const int blk = blockIdx.x;
  const int tid = threadIdx.x;
  if (blk < 64) {
    __shared__ float qs[DIM];
    for (int i = tid; i < DIM; i += 256) qs[i] = query[blk * DIM + i];
    __syncthreads();
    for (int o = tid; o < DIM; o += 256) {
      const float* w = Wq + o * DIM;
      float acc = 0.f;
      for (int k = 0; k < DIM; k += 4) {
        f32x4 a = *(const f32x4*)&qs[k];
        f32x4 b = *(const f32x4*)&w[k];
        acc += a.x * b.x + a.y * b.y + a.z * b.z + a.w * b.w;
      }
      q_out[blk * DIM + o] = acc + bq[o];
    }
  } else {
    const int c = blk - 64;
    const int flat = c * 4096 + tid * 16;
    const int o = flat >> 9, k0 = flat & 511;
    const int t = k0 >> 5, kk = k0 & 31;
    u16* dst = Wrbt + t * 16384 + o * 32 + kk;
#pragma unroll
    for (int i = 0; i < 4; ++i) {
      f32x4 a = *(const f32x4*)&Wr[flat + i * 4];
      s16x4 o4;
      o4.x = (short)f2bf(a.x); o4.y = (short)f2bf(a.y);
      o4.z = (short)f2bf(a.z); o4.w = (short)f2bf(a.w);
      *(s16x4*)&dst[i * 4] = o4;
    }
  }
}

// ---------- fused GEMM: persistent 2-tile blocks, all barriers lgkm-only ----------
// grid 512; block does tiles bid and bid+512 (flat = lt*64+b). Tile-1's nt
// stores drain UNDER tile-2's prologue+K-loop reads (no vmcnt(0) anywhere).
// Per tile: R17's body -- depth-2 ref prefetch, af ping-pong, counted barriers,
// setprio MFMA, register tanh/logits, 16-phase Ebuf repack (512B-run stores).
__global__ __launch_bounds__(1024, 4) void gemm_fused(
    const float* __restrict__ ref, const u16* __restrict__ Wrbt,
    const float* __restrict__ q, const float* __restrict__ br,
    const float* __restrict__ v, float* __restrict__ e_out,
    float* __restrict__ logits) {
  __shared__ u16 Bs[2][128 * 40];      // 20,480 B
  __shared__ float Ebuf[2][32 * 132];  // 33,792 B
  __shared__ float u_lds[16][64];      //  4,096 B

  const int bid = blockIdx.x;
  const int tid = threadIdx.x, lane = tid & 63, wid = tid >> 6;
  const int og = wid >> 1, lg = wid & 1;
  const int rr = lane & 15, kg = lane >> 4;
  const int srow = tid >> 3, sc8 = tid & 7;

  const u16* ap = Wrbt + (og * 64 + rr) * 32 + kg * 8;

  for (int tp = 0; tp < 2; ++tp) {
    const int f = bid + tp * 512;
    const int b = f & 63, lt = f >> 6;
    const int l0 = lt * 128;
    const size_t refbase = ((size_t)(l0 + srow) * 64 + b) * 512 + sc8 * 4;

    // ---- prologue: stage slice 0; issue slice 1 + af[0]; counted barrier ----
    f32x4 srIF;
    s16x8 afP[4], afQ[4];
    {
      f32x4 a = __builtin_nontemporal_load((const f32x4*)&ref[refbase]);
      s16x4 o4;
      o4.x = (short)f2bf(a.x); o4.y = (short)f2bf(a.y);
      o4.z = (short)f2bf(a.z); o4.w = (short)f2bf(a.w);
      *(s16x4*)&Bs[0][srow * 40 + sc8 * 4] = o4;
      srIF = __builtin_nontemporal_load((const f32x4*)&ref[refbase + 32]);
#pragma unroll
      for (int fm = 0; fm < 4; ++fm)
        afP[fm] = *(const s16x8*)(ap + fm * 512);
    }
    LGKM_BAR();

    f32x4 acc[4][4];
#pragma unroll
    for (int fm = 0; fm < 4; ++fm)
#pragma unroll
      for (int fn = 0; fn < 4; ++fn) acc[fm][fn] = (f32x4){0.f, 0.f, 0.f, 0.f};

#pragma unroll
    for (int tt = 0; tt < 8; ++tt) {
      const int t0 = tt * 2, t1 = t0 + 1;
      // ======== step t0: Bs[0], MFMA afP; prefetch afQ = af[t1] ========
      {
        f32x4 srN;
        if (t0 < 14)
          srN = __builtin_nontemporal_load((const f32x4*)&ref[refbase + (t0 + 2) * 32]);
#pragma unroll
        for (int fm = 0; fm < 4; ++fm)
          afQ[fm] = *(const s16x8*)(ap + t1 * 16384 + fm * 512);
        s16x8 bf[4];
#pragma unroll
        for (int fn = 0; fn < 4; ++fn)
          bf[fn] = *(const s16x8*)&Bs[0][(lg * 64 + fn * 16 + rr) * 40 + kg * 8];
        __builtin_amdgcn_s_setprio(1);
#pragma unroll
        for (int fm = 0; fm < 4; ++fm)
#pragma unroll
          for (int fn = 0; fn < 4; ++fn)
            acc[fm][fn] = __builtin_amdgcn_mfma_f32_16x16x32_bf16(bf[fn], afP[fm], acc[fm][fn], 0, 0, 0);
        __builtin_amdgcn_s_setprio(0);
        {
          s16x4 o4;
          o4.x = (short)f2bf(srIF.x); o4.y = (short)f2bf(srIF.y);
          o4.z = (short)f2bf(srIF.z); o4.w = (short)f2bf(srIF.w);
          *(s16x4*)&Bs[1][srow * 40 + sc8 * 4] = o4;
        }
        LGKM_BAR();
        if (t0 < 14) srIF = srN;
      }
      // ======== step t1: Bs[1], MFMA afQ; prefetch afP = af[t1+1] ========
      {
        f32x4 srN;
        if (t1 < 14)
          srN = __builtin_nontemporal_load((const f32x4*)&ref[refbase + (t1 + 2) * 32]);
        if (t1 < 15)
#pragma unroll
          for (int fm = 0; fm < 4; ++fm)
            afP[fm] = *(const s16x8*)(ap + (t1 + 1) * 16384 + fm * 512);
        s16x8 bf[4];
#pragma unroll
        for (int fn = 0; fn < 4; ++fn)
          bf[fn] = *(const s16x8*)&Bs[1][(lg * 64 + fn * 16 + rr) * 40 + kg * 8];
        __builtin_amdgcn_s_setprio(1);
#pragma unroll
        for (int fm = 0; fm < 4; ++fm)
#pragma unroll
          for (int fn = 0; fn < 4; ++fn)
            acc[fm][fn] = __builtin_amdgcn_mfma_f32_16x16x32_bf16(bf[fn], afQ[fm], acc[fm][fn], 0, 0, 0);
        __builtin_amdgcn_s_setprio(0);
        if (t1 < 15) {
          {
            s16x4 o4;
            o4.x = (short)f2bf(srIF.x); o4.y = (short)f2bf(srIF.y);
            o4.z = (short)f2bf(srIF.z); o4.w = (short)f2bf(srIF.w);
            *(s16x4*)&Bs[0][srow * 40 + sc8 * 4] = o4;
          }
          LGKM_BAR();
          if (t1 < 14) srIF = srN;
        }
      }
    }

    // ---- tanh / logits partials (register-only) ----
    float bb[4];
    f32x4 usA[4];
#pragma unroll
    for (int fn = 0; fn < 4; ++fn) usA[fn] = (f32x4){0.f, 0.f, 0.f, 0.f};
#pragma unroll
    for (int fm = 0; fm < 4; ++fm) {
      const int o = og * 64 + fm * 16 + rr;
      bb[fm] = br[o];
      const float qv = q[b * DIM + o] + bb[fm];
      const float vv = v[o];
#pragma unroll
      for (int fn = 0; fn < 4; ++fn) {
        f32x4 a = acc[fm][fn];
        f32x4 th;
        th.x = tanh_fast(a.x + qv);
        th.y = tanh_fast(a.y + qv);
        th.z = tanh_fast(a.z + qv);
        th.w = tanh_fast(a.w + qv);
        usA[fn] += vv * th;
      }
    }
#pragma unroll
    for (int fn = 0; fn < 4; ++fn) {
      f32x4 us = usA[fn];
#pragma unroll
      for (int msk = 1; msk <= 8; msk <<= 1) {  // reduce over rr (o dim)
        us.x += __shfl_xor(us.x, msk);
        us.y += __shfl_xor(us.y, msk);
        us.z += __shfl_xor(us.z, msk);
        us.w += __shfl_xor(us.w, msk);
      }
      if (rr == 0)
        *(f32x4*)&u_lds[wid][fn * 16 + kg * 4] = us;
    }

    // ---- e-store: 16 repack phases, lgkm-only barriers; stores pipeline ----
#pragma unroll 2
    for (int ph = 0; ph < 16; ++ph) {
      float* Eb = &Ebuf[ph & 1][0];
      if (og == (ph >> 1)) {
        const int f2b = (ph & 1) * 2;
#pragma unroll
        for (int f2 = 0; f2 < 2; ++f2) {
          const int fm = f2b + f2;
#pragma unroll
          for (int fn = 0; fn < 4; ++fn) {
            f32x4 ev = acc[fm][fn] + bb[fm];
            *(f32x4*)&Eb[(f2 * 16 + rr) * 132 + lg * 64 + fn * 16 + kg * 4] = ev;
          }
        }
      }
      LGKM_BAR();
      {
        const int op = tid >> 5, lc4 = (tid & 31) * 4;
        f32x4 ev = *(const f32x4*)&Eb[op * 132 + lc4];
        __builtin_nontemporal_store(
            ev, (f32x4*)&e_out[((size_t)(b * DIM + ph * 32 + op)) * L_ + l0 + lc4]);
      }
      LGKM_BAR();  // Eb reads done -> buffer reusable at ph+2 (vmem NOT drained)
    }

    // ---- logits ----
    if (tid < 128) {
      const int ll = tid & 63, lgi = tid >> 6;
      float s = 0.f;
#pragma unroll
      for (int o8 = 0; o8 < 8; ++o8) s += u_lds[o8 * 2 + lgi][ll];
      logits[(size_t)b * L_ + l0 + lgi * 64 + ll] = s;
    }
    LGKM_BAR();  // u_lds/Bs safe for next tile
  }
}

extern "C" void kernel_launch(void* const* d_in, const int* in_sizes, int n_in,
                              void* d_out, int out_size, void* d_ws, size_t ws_size,
                              hipStream_t stream) {
  const float* query = (const float*)d_in[0];
  const float* ref   = (const float*)d_in[1];
  const float* Wq    = (const float*)d_in[2];
  const float* bq    = (const float*)d_in[3];
  const float* Wr    = (const float*)d_in[4];
  const float* br    = (const float*)d_in[5];
  const float* v     = (const float*)d_in[6];

  float* e_out  = (float*)d_out;
  float* logits = e_out + (size_t)B_ * DIM * L_;  // 67108864

  char* ws = (char*)d_ws;
  u16*   Wrbt = (u16*)ws;               // 512 KB [16][512][32]
  float* q    = (float*)(ws + 524288);  // 128 KB

  prep_kernel<<<128, 256, 0, stream>>>(query, Wq, bq, Wr, q, Wrbt);
  gemm_fused<<<512, 1024, 0, stream>>>(ref, Wrbt, q, br, v, e_out, logits);
}

// Round 19
// 215.004 us; speedup vs baseline: 1.8520x; 1.8520x over previous
//
#include <hip/hip_runtime.h>

#define DIM 512
#define B_  64
#define L_  2048

typedef unsigned short u16;
typedef float f32x4 __attribute__((ext_vector_type(4)));
typedef short s16x8 __attribute__((ext_vector_type(8)));
typedef short s16x4 __attribute__((ext_vector_type(4)));

__device__ __forceinline__ u16 f2bf(float f) {
  union { float f; unsigned u; } x{f};
  unsigned r = x.u + 0x7FFFu + ((x.u >> 16) & 1u);
  return (u16)(r >> 16);
}

__device__ __forceinline__ float tanh_fast(float x) {
  float e2 = __expf(2.0f * x);
  return 1.0f - 2.0f / (e2 + 1.0f);
}

// ---------- prep: q = query @ Wq^T + bq ; Wr -> bf16 transposed [t][o][32k] ----------
__global__ __launch_bounds__(256) void prep_kernel(
    const float* __restrict__ query, const float* __restrict__ Wq,
    const float* __restrict__ bq, const float* __restrict__ Wr,
    float* __restrict__ q_out, u16* __restrict__ Wrbt) {
  const int blk = blockIdx.x;
  const int tid = threadIdx.x;
  if (blk < 64) {
    __shared__ float qs[DIM];
    for (int i = tid; i < DIM; i += 256) qs[i] = query[blk * DIM + i];
    __syncthreads();
    for (int o = tid; o < DIM; o += 256) {
      const float* w = Wq + o * DIM;
      float acc = 0.f;
      for (int k = 0; k < DIM; k += 4) {
        f32x4 a = *(const f32x4*)&qs[k];
        f32x4 b = *(const f32x4*)&w[k];
        acc += a.x * b.x + a.y * b.y + a.z * b.z + a.w * b.w;
      }
      q_out[blk * DIM + o] = acc + bq[o];
    }
  } else {
    const int c = blk - 64;
    const int flat = c * 4096 + tid * 16;
    const int o = flat >> 9, k0 = flat & 511;
    const int t = k0 >> 5, kk = k0 & 31;
    u16* dst = Wrbt + t * 16384 + o * 32 + kk;
#pragma unroll
    for (int i = 0; i < 4; ++i) {
      f32x4 a = *(const f32x4*)&Wr[flat + i * 4];
      s16x4 o4;
      o4.x = (short)f2bf(a.x); o4.y = (short)f2bf(a.y);
      o4.z = (short)f2bf(a.z); o4.w = (short)f2bf(a.w);
      *(s16x4*)&dst[i * 4] = o4;
    }
  }
}

// ---------- fused GEMM: 512o x 128l; depth-2 ref prefetch + af ping-pong ----------
// Verified best (R17). Per K-step: counted barrier (lgkmcnt(0) + s_barrier,
// vmem in flight), depth-2 ref slice prefetch, af (Wrbt) ping-pong issued one
// step ahead, setprio around the MFMA cluster. Epilogue: register tanh/logits,
// 16-phase Ebuf repack -> each e-store instruction = 2 rows x 512 B contiguous.
__global__ __launch_bounds__(1024, 4) void gemm_fused(
    const float* __restrict__ ref, const u16* __restrict__ Wrbt,
    const float* __restrict__ q, const float* __restrict__ br,
    const float* __restrict__ v, float* __restrict__ e_out,
    float* __restrict__ logits) {
  __shared__ u16 Bs[2][128 * 40];      // 20,480 B
  __shared__ float Ebuf[2][32 * 132];  // 33,792 B
  __shared__ float u_lds[16][64];      //  4,096 B

  const int b = blockIdx.x, lt = blockIdx.y;
  const int l0 = lt * 128;
  const int tid = threadIdx.x, lane = tid & 63, wid = tid >> 6;
  const int og = wid >> 1, lg = wid & 1;
  const int rr = lane & 15, kg = lane >> 4;
  const int srow = tid >> 3, sc8 = tid & 7;

  const size_t refbase = ((size_t)(l0 + srow) * 64 + b) * 512 + sc8 * 4;
  const u16* ap = Wrbt + (og * 64 + rr) * 32 + kg * 8;

  // ---- prologue: stage slice 0; issue slice 1 + af[0]; counted barrier ----
  f32x4 srIF;
  s16x8 afP[4], afQ[4];
  {
    f32x4 a = __builtin_nontemporal_load((const f32x4*)&ref[refbase]);
    s16x4 o4;
    o4.x = (short)f2bf(a.x); o4.y = (short)f2bf(a.y);
    o4.z = (short)f2bf(a.z); o4.w = (short)f2bf(a.w);
    *(s16x4*)&Bs[0][srow * 40 + sc8 * 4] = o4;
    srIF = __builtin_nontemporal_load((const f32x4*)&ref[refbase + 32]);
#pragma unroll
    for (int fm = 0; fm < 4; ++fm)
      afP[fm] = *(const s16x8*)(ap + fm * 512);
  }
  asm volatile("s_waitcnt lgkmcnt(0)" ::: "memory");
  __builtin_amdgcn_s_barrier();
  __builtin_amdgcn_sched_barrier(0);

  f32x4 acc[4][4];
#pragma unroll
  for (int fm = 0; fm < 4; ++fm)
#pragma unroll
    for (int fn = 0; fn < 4; ++fn) acc[fm][fn] = (f32x4){0.f, 0.f, 0.f, 0.f};

#pragma unroll
  for (int tt = 0; tt < 8; ++tt) {
    const int t0 = tt * 2, t1 = t0 + 1;
    // ======== step t0: Bs[0], MFMA with afP; prefetch afQ = af[t1] ========
    {
      f32x4 srN;
      if (t0 < 14)
        srN = __builtin_nontemporal_load((const f32x4*)&ref[refbase + (t0 + 2) * 32]);
#pragma unroll
      for (int fm = 0; fm < 4; ++fm)
        afQ[fm] = *(const s16x8*)(ap + t1 * 16384 + fm * 512);
      s16x8 bf[4];
#pragma unroll
      for (int fn = 0; fn < 4; ++fn)
        bf[fn] = *(const s16x8*)&Bs[0][(lg * 64 + fn * 16 + rr) * 40 + kg * 8];
      __builtin_amdgcn_s_setprio(1);
#pragma unroll
      for (int fm = 0; fm < 4; ++fm)
#pragma unroll
        for (int fn = 0; fn < 4; ++fn)
          acc[fm][fn] = __builtin_amdgcn_mfma_f32_16x16x32_bf16(bf[fn], afP[fm], acc[fm][fn], 0, 0, 0);
      __builtin_amdgcn_s_setprio(0);
      {  // stage slice t0+1 into Bs[1]
        s16x4 o4;
        o4.x = (short)f2bf(srIF.x); o4.y = (short)f2bf(srIF.y);
        o4.z = (short)f2bf(srIF.z); o4.w = (short)f2bf(srIF.w);
        *(s16x4*)&Bs[1][srow * 40 + sc8 * 4] = o4;
      }
      asm volatile("s_waitcnt lgkmcnt(0)" ::: "memory");
      __builtin_amdgcn_s_barrier();
      __builtin_amdgcn_sched_barrier(0);
      if (t0 < 14) srIF = srN;
    }
    // ======== step t1: Bs[1], MFMA with afQ; prefetch afP = af[t1+1] ========
    {
      f32x4 srN;
      if (t1 < 14)
        srN = __builtin_nontemporal_load((const f32x4*)&ref[refbase + (t1 + 2) * 32]);
      if (t1 < 15)
#pragma unroll
        for (int fm = 0; fm < 4; ++fm)
          afP[fm] = *(const s16x8*)(ap + (t1 + 1) * 16384 + fm * 512);
      s16x8 bf[4];
#pragma unroll
      for (int fn = 0; fn < 4; ++fn)
        bf[fn] = *(const s16x8*)&Bs[1][(lg * 64 + fn * 16 + rr) * 40 + kg * 8];
      __builtin_amdgcn_s_setprio(1);
#pragma unroll
      for (int fm = 0; fm < 4; ++fm)
#pragma unroll
        for (int fn = 0; fn < 4; ++fn)
          acc[fm][fn] = __builtin_amdgcn_mfma_f32_16x16x32_bf16(bf[fn], afQ[fm], acc[fm][fn], 0, 0, 0);
      __builtin_amdgcn_s_setprio(0);
      if (t1 < 15) {
        {  // stage slice t1+1 into Bs[0]
          s16x4 o4;
          o4.x = (short)f2bf(srIF.x); o4.y = (short)f2bf(srIF.y);
          o4.z = (short)f2bf(srIF.z); o4.w = (short)f2bf(srIF.w);
          *(s16x4*)&Bs[0][srow * 40 + sc8 * 4] = o4;
        }
        asm volatile("s_waitcnt lgkmcnt(0)" ::: "memory");
        __builtin_amdgcn_s_barrier();
        __builtin_amdgcn_sched_barrier(0);
        if (t1 < 14) srIF = srN;
      }
    }
  }

  // ---- tanh / logits partials (register-only) ----
  float bb[4];
  f32x4 usA[4];
#pragma unroll
  for (int fn = 0; fn < 4; ++fn) usA[fn] = (f32x4){0.f, 0.f, 0.f, 0.f};
#pragma unroll
  for (int fm = 0; fm < 4; ++fm) {
    const int o = og * 64 + fm * 16 + rr;
    bb[fm] = br[o];
    const float qv = q[b * DIM + o] + bb[fm];
    const float vv = v[o];
#pragma unroll
    for (int fn = 0; fn < 4; ++fn) {
      f32x4 a = acc[fm][fn];
      f32x4 th;
      th.x = tanh_fast(a.x + qv);
      th.y = tanh_fast(a.y + qv);
      th.z = tanh_fast(a.z + qv);
      th.w = tanh_fast(a.w + qv);
      usA[fn] += vv * th;
    }
  }
#pragma unroll
  for (int fn = 0; fn < 4; ++fn) {
    f32x4 us = usA[fn];
#pragma unroll
    for (int msk = 1; msk <= 8; msk <<= 1) {  // reduce over rr (o dim)
      us.x += __shfl_xor(us.x, msk);
      us.y += __shfl_xor(us.y, msk);
      us.z += __shfl_xor(us.z, msk);
      us.w += __shfl_xor(us.w, msk);
    }
    if (rr == 0)
      *(f32x4*)&u_lds[wid][fn * 16 + kg * 4] = us;
  }

  // ---- e-store: 16 ping-pong repack phases; store = 2 rows x 512 B ----
#pragma unroll 2
  for (int ph = 0; ph < 16; ++ph) {
    float* Eb = &Ebuf[ph & 1][0];
    if (og == (ph >> 1)) {
      const int f2b = (ph & 1) * 2;
#pragma unroll
      for (int f2 = 0; f2 < 2; ++f2) {
        const int fm = f2b + f2;
#pragma unroll
        for (int fn = 0; fn < 4; ++fn) {
          f32x4 ev = acc[fm][fn] + bb[fm];
          *(f32x4*)&Eb[(f2 * 16 + rr) * 132 + lg * 64 + fn * 16 + kg * 4] = ev;
        }
      }
    }
    __syncthreads();
    {
      const int op = tid >> 5, lc4 = (tid & 31) * 4;
      f32x4 ev = *(const f32x4*)&Eb[op * 132 + lc4];
      __builtin_nontemporal_store(
          ev, (f32x4*)&e_out[((size_t)(b * DIM + ph * 32 + op)) * L_ + l0 + lc4]);
    }
  }

  // ---- logits ----
  __syncthreads();
  if (tid < 128) {
    const int ll = tid & 63, lgi = tid >> 6;
    float s = 0.f;
#pragma unroll
    for (int o8 = 0; o8 < 8; ++o8) s += u_lds[o8 * 2 + lgi][ll];
    logits[(size_t)b * L_ + l0 + lgi * 64 + ll] = s;
  }
}

extern "C" void kernel_launch(void* const* d_in, const int* in_sizes, int n_in,
                              void* d_out, int out_size, void* d_ws, size_t ws_size,
                              hipStream_t stream) {
  const float* query = (const float*)d_in[0];
  const float* ref   = (const float*)d_in[1];
  const float* Wq    = (const float*)d_in[2];
  const float* bq    = (const float*)d_in[3];
  const float* Wr    = (const float*)d_in[4];
  const float* br    = (const float*)d_in[5];
  const float* v     = (const float*)d_in[6];

  float* e_out  = (float*)d_out;
  float* logits = e_out + (size_t)B_ * DIM * L_;  // 67108864

  char* ws = (char*)d_ws;
  u16*   Wrbt = (u16*)ws;               // 512 KB [16][512][32]
  float* q    = (float*)(ws + 524288);  // 128 KB

  prep_kernel<<<128, 256, 0, stream>>>(query, Wq, bq, Wr, q, Wrbt);
  gemm_fused<<<dim3(64, 16), 1024, 0, stream>>>(ref, Wrbt, q, br, v, e_out, logits);
}

// Round 20
// 214.432 us; speedup vs baseline: 1.8570x; 1.0027x over previous
//
#include <hip/hip_runtime.h>
#include <hip/hip_bf16.h>

#define DIM 512
#define B_  64
#define L_  2048

typedef unsigned short u16;
typedef float f32x4 __attribute__((ext_vector_type(4)));
typedef short s16x8 __attribute__((ext_vector_type(8)));
typedef short s16x4 __attribute__((ext_vector_type(4)));

__device__ __forceinline__ u16 f2bf(float f) {
  union { float f; unsigned u; } x{f};
  unsigned r = x.u + 0x7FFFu + ((x.u >> 16) & 1u);
  return (u16)(r >> 16);
}

// compiler-recognized bf16 cast path (emits v_cvt hardware instrs, RNE)
__device__ __forceinline__ s16x4 cvt4(f32x4 a) {
  __hip_bfloat16 h0 = __float2bfloat16(a.x);
  __hip_bfloat16 h1 = __float2bfloat16(a.y);
  __hip_bfloat16 h2 = __float2bfloat16(a.z);
  __hip_bfloat16 h3 = __float2bfloat16(a.w);
  s16x4 r;
  r.x = *(short*)&h0; r.y = *(short*)&h1;
  r.z = *(short*)&h2; r.w = *(short*)&h3;
  return r;
}

__device__ __forceinline__ float tanh_fast(float x) {
  float e2 = __expf(2.0f * x);
  return 1.0f - 2.0f / (e2 + 1.0f);
}

// ---------- prep: q = query @ Wq^T + bq ; Wr -> bf16 transposed [t][o][32k] ----------
__global__ __launch_bounds__(256) void prep_kernel(
    const float* __restrict__ query, const float* __restrict__ Wq,
    const float* __restrict__ bq, const float* __restrict__ Wr,
    float* __restrict__ q_out, u16* __restrict__ Wrbt) {
  const int blk = blockIdx.x;
  const int tid = threadIdx.x;
  if (blk < 64) {
    __shared__ float qs[DIM];
    for (int i = tid; i < DIM; i += 256) qs[i] = query[blk * DIM + i];
    __syncthreads();
    for (int o = tid; o < DIM; o += 256) {
      const float* w = Wq + o * DIM;
      float acc = 0.f;
      for (int k = 0; k < DIM; k += 4) {
        f32x4 a = *(const f32x4*)&qs[k];
        f32x4 b = *(const f32x4*)&w[k];
        acc += a.x * b.x + a.y * b.y + a.z * b.z + a.w * b.w;
      }
      q_out[blk * DIM + o] = acc + bq[o];
    }
  } else {
    const int c = blk - 64;
    const int flat = c * 4096 + tid * 16;
    const int o = flat >> 9, k0 = flat & 511;
    const int t = k0 >> 5, kk = k0 & 31;
    u16* dst = Wrbt + t * 16384 + o * 32 + kk;
#pragma unroll
    for (int i = 0; i < 4; ++i) {
      f32x4 a = *(const f32x4*)&Wr[flat + i * 4];
      s16x4 o4;
      o4.x = (short)f2bf(a.x); o4.y = (short)f2bf(a.y);
      o4.z = (short)f2bf(a.z); o4.w = (short)f2bf(a.w);
      *(s16x4*)&dst[i * 4] = o4;
    }
  }
}

// ---------- fused GEMM: 512o x 128l; depth-2 ref prefetch + af ping-pong ----------
// R17 structure (verified best). Only change: staging f32->bf16 uses the
// compiler cast path (v_cvt hardware instrs) instead of bit-manip f2bf.
__global__ __launch_bounds__(1024, 4) void gemm_fused(
    const float* __restrict__ ref, const u16* __restrict__ Wrbt,
    const float* __restrict__ q, const float* __restrict__ br,
    const float* __restrict__ v, float* __restrict__ e_out,
    float* __restrict__ logits) {
  __shared__ u16 Bs[2][128 * 40];      // 20,480 B
  __shared__ float Ebuf[2][32 * 132];  // 33,792 B
  __shared__ float u_lds[16][64];      //  4,096 B

  const int b = blockIdx.x, lt = blockIdx.y;
  const int l0 = lt * 128;
  const int tid = threadIdx.x, lane = tid & 63, wid = tid >> 6;
  const int og = wid >> 1, lg = wid & 1;
  const int rr = lane & 15, kg = lane >> 4;
  const int srow = tid >> 3, sc8 = tid & 7;

  const size_t refbase = ((size_t)(l0 + srow) * 64 + b) * 512 + sc8 * 4;
  const u16* ap = Wrbt + (og * 64 + rr) * 32 + kg * 8;

  // ---- prologue: stage slice 0; issue slice 1 + af[0]; counted barrier ----
  f32x4 srIF;
  s16x8 afP[4], afQ[4];
  {
    f32x4 a = __builtin_nontemporal_load((const f32x4*)&ref[refbase]);
    *(s16x4*)&Bs[0][srow * 40 + sc8 * 4] = cvt4(a);
    srIF = __builtin_nontemporal_load((const f32x4*)&ref[refbase + 32]);
#pragma unroll
    for (int fm = 0; fm < 4; ++fm)
      afP[fm] = *(const s16x8*)(ap + fm * 512);
  }
  asm volatile("s_waitcnt lgkmcnt(0)" ::: "memory");
  __builtin_amdgcn_s_barrier();
  __builtin_amdgcn_sched_barrier(0);

  f32x4 acc[4][4];
#pragma unroll
  for (int fm = 0; fm < 4; ++fm)
#pragma unroll
    for (int fn = 0; fn < 4; ++fn) acc[fm][fn] = (f32x4){0.f, 0.f, 0.f, 0.f};

#pragma unroll
  for (int tt = 0; tt < 8; ++tt) {
    const int t0 = tt * 2, t1 = t0 + 1;
    // ======== step t0: Bs[0], MFMA with afP; prefetch afQ = af[t1] ========
    {
      f32x4 srN;
      if (t0 < 14)
        srN = __builtin_nontemporal_load((const f32x4*)&ref[refbase + (t0 + 2) * 32]);
#pragma unroll
      for (int fm = 0; fm < 4; ++fm)
        afQ[fm] = *(const s16x8*)(ap + t1 * 16384 + fm * 512);
      s16x8 bf[4];
#pragma unroll
      for (int fn = 0; fn < 4; ++fn)
        bf[fn] = *(const s16x8*)&Bs[0][(lg * 64 + fn * 16 + rr) * 40 + kg * 8];
      __builtin_amdgcn_s_setprio(1);
#pragma unroll
      for (int fm = 0; fm < 4; ++fm)
#pragma unroll
        for (int fn = 0; fn < 4; ++fn)
          acc[fm][fn] = __builtin_amdgcn_mfma_f32_16x16x32_bf16(bf[fn], afP[fm], acc[fm][fn], 0, 0, 0);
      __builtin_amdgcn_s_setprio(0);
      *(s16x4*)&Bs[1][srow * 40 + sc8 * 4] = cvt4(srIF);  // stage slice t0+1
      asm volatile("s_waitcnt lgkmcnt(0)" ::: "memory");
      __builtin_amdgcn_s_barrier();
      __builtin_amdgcn_sched_barrier(0);
      if (t0 < 14) srIF = srN;
    }
    // ======== step t1: Bs[1], MFMA with afQ; prefetch afP = af[t1+1] ========
    {
      f32x4 srN;
      if (t1 < 14)
        srN = __builtin_nontemporal_load((const f32x4*)&ref[refbase + (t1 + 2) * 32]);
      if (t1 < 15)
#pragma unroll
        for (int fm = 0; fm < 4; ++fm)
          afP[fm] = *(const s16x8*)(ap + (t1 + 1) * 16384 + fm * 512);
      s16x8 bf[4];
#pragma unroll
      for (int fn = 0; fn < 4; ++fn)
        bf[fn] = *(const s16x8*)&Bs[1][(lg * 64 + fn * 16 + rr) * 40 + kg * 8];
      __builtin_amdgcn_s_setprio(1);
#pragma unroll
      for (int fm = 0; fm < 4; ++fm)
#pragma unroll
        for (int fn = 0; fn < 4; ++fn)
          acc[fm][fn] = __builtin_amdgcn_mfma_f32_16x16x32_bf16(bf[fn], afQ[fm], acc[fm][fn], 0, 0, 0);
      __builtin_amdgcn_s_setprio(0);
      if (t1 < 15) {
        *(s16x4*)&Bs[0][srow * 40 + sc8 * 4] = cvt4(srIF);  // stage slice t1+1
        asm volatile("s_waitcnt lgkmcnt(0)" ::: "memory");
        __builtin_amdgcn_s_barrier();
        __builtin_amdgcn_sched_barrier(0);
        if (t1 < 14) srIF = srN;
      }
    }
  }

  // ---- tanh / logits partials (register-only) ----
  float bb[4];
  f32x4 usA[4];
#pragma unroll
  for (int fn = 0; fn < 4; ++fn) usA[fn] = (f32x4){0.f, 0.f, 0.f, 0.f};
#pragma unroll
  for (int fm = 0; fm < 4; ++fm) {
    const int o = og * 64 + fm * 16 + rr;
    bb[fm] = br[o];
    const float qv = q[b * DIM + o] + bb[fm];
    const float vv = v[o];
#pragma unroll
    for (int fn = 0; fn < 4; ++fn) {
      f32x4 a = acc[fm][fn];
      f32x4 th;
      th.x = tanh_fast(a.x + qv);
      th.y = tanh_fast(a.y + qv);
      th.z = tanh_fast(a.z + qv);
      th.w = tanh_fast(a.w + qv);
      usA[fn] += vv * th;
    }
  }
#pragma unroll
  for (int fn = 0; fn < 4; ++fn) {
    f32x4 us = usA[fn];
#pragma unroll
    for (int msk = 1; msk <= 8; msk <<= 1) {  // reduce over rr (o dim)
      us.x += __shfl_xor(us.x, msk);
      us.y += __shfl_xor(us.y, msk);
      us.z += __shfl_xor(us.z, msk);
      us.w += __shfl_xor(us.w, msk);
    }
    if (rr == 0)
      *(f32x4*)&u_lds[wid][fn * 16 + kg * 4] = us;
  }

  // ---- e-store: 16 ping-pong repack phases; store = 2 rows x 512 B ----
#pragma unroll 2
  for (int ph = 0; ph < 16; ++ph) {
    float* Eb = &Ebuf[ph & 1][0];
    if (og == (ph >> 1)) {
      const int f2b = (ph & 1) * 2;
#pragma unroll
      for (int f2 = 0; f2 < 2; ++f2) {
        const int fm = f2b + f2;
#pragma unroll
        for (int fn = 0; fn < 4; ++fn) {
          f32x4 ev = acc[fm][fn] + bb[fm];
          *(f32x4*)&Eb[(f2 * 16 + rr) * 132 + lg * 64 + fn * 16 + kg * 4] = ev;
        }
      }
    }
    __syncthreads();
    {
      const int op = tid >> 5, lc4 = (tid & 31) * 4;
      f32x4 ev = *(const f32x4*)&Eb[op * 132 + lc4];
      __builtin_nontemporal_store(
          ev, (f32x4*)&e_out[((size_t)(b * DIM + ph * 32 + op)) * L_ + l0 + lc4]);
    }
  }

  // ---- logits ----
  __syncthreads();
  if (tid < 128) {
    const int ll = tid & 63, lgi = tid >> 6;
    float s = 0.f;
#pragma unroll
    for (int o8 = 0; o8 < 8; ++o8) s += u_lds[o8 * 2 + lgi][ll];
    logits[(size_t)b * L_ + l0 + lgi * 64 + ll] = s;
  }
}

extern "C" void kernel_launch(void* const* d_in, const int* in_sizes, int n_in,
                              void* d_out, int out_size, void* d_ws, size_t ws_size,
                              hipStream_t stream) {
  const float* query = (const float*)d_in[0];
  const float* ref   = (const float*)d_in[1];
  const float* Wq    = (const float*)d_in[2];
  const float* bq    = (const float*)d_in[3];
  const float* Wr    = (const float*)d_in[4];
  const float* br    = (const float*)d_in[5];
  const float* v     = (const float*)d_in[6];

  float* e_out  = (float*)d_out;
  float* logits = e_out + (size_t)B_ * DIM * L_;  // 67108864

  char* ws = (char*)d_ws;
  u16*   Wrbt = (u16*)ws;               // 512 KB [16][512][32]
  float* q    = (float*)(ws + 524288);  // 128 KB

  prep_kernel<<<128, 256, 0, stream>>>(query, Wq, bq, Wr, q, Wrbt);
  gemm_fused<<<dim3(64, 16), 1024, 0, stream>>>(ref, Wrbt, q, br, v, e_out, logits);
}